// Round 15
// baseline (181.322 us; speedup 1.0000x reference)
//
#include <hip/hip_runtime.h>

#define NNODE 50000
#define NEDGE 600000
#define KDIN  239
#define DDIM  128
#define NTILES 3125           // 3125*16 == 50000 exactly
#define NBG   782             // one-shot gemm blocks: 782*4 waves >= 3125 tiles
#define NBUCK 256             // coarse dst buckets
#define BSZ   196             // dsts per bucket (196*256 >= 50000)
#define HBSZ  98              // dsts per fineagg half-block (BSZ/2)
#define NPB   128             // partition/hist blocks
#define CHP   4688            // edges per hist/partition block (128*4688 >= 600000)
#define ESCAP 4096            // LDS CSR capacity per bucket (global fallback if exceeded)

typedef _Float16 half8 __attribute__((ext_vector_type(8)));
typedef _Float16 half4 __attribute__((ext_vector_type(4)));
typedef __attribute__((ext_vector_type(4))) float f32x4;

__device__ __forceinline__ ushort f2h(float f){
  union { _Float16 h; ushort u; } c; c.h = (_Float16)f; return c.u;
}

// ---- prologue: coarse LDS histogram (block-major cpart counts) || weight transposes ----
__global__ __launch_bounds__(256) void pre_k(
    const float* __restrict__ W_in, const float* __restrict__ W_gat, const float* __restrict__ W_h,
    ushort* __restrict__ BfA, ushort* __restrict__ BfB, ushort* __restrict__ BfC,
    const int* __restrict__ ei, int* __restrict__ cpart)
{
  __shared__ int hb[NBUCK];
  const int b = blockIdx.x, t = threadIdx.x;
  if (b < NPB){                                    // coarse histogram, single sweep
    hb[t] = 0;
    __syncthreads();
    const int e0 = b*CHP, e1 = min(NEDGE, e0+CHP);
    for (int e=e0+t; e<e1; e+=256){
      int dst = min(max(ei[NEDGE+e],0), NNODE-1);
      atomicAdd(&hb[dst/BSZ], 1);                  // LDS atomic, 256 bins
    }
    __syncthreads();
    cpart[b*NBUCK + t] = hb[t];                    // block-major: coalesced write
  } else if (b < NPB + 128){                       // W_in [239,128] -> BfA[n=128][k=256]
    int idx = (b-NPB)*256 + t; int n = idx >> 8, k = idx & 255;
    BfA[idx] = (k < KDIN) ? f2h(W_in[(size_t)k*DDIM + n]) : (ushort)0;
  } else if (b < NPB + 192){                       // W_gat -> BfB[n][128]
    int idx = (b-NPB-128)*256 + t; int n = idx >> 7, k = idx & 127;
    BfB[idx] = f2h(W_gat[(size_t)k*DDIM + n]);
  } else {                                         // W_h -> BfC[n][128]
    int idx = (b-NPB-192)*256 + t; int n = idx >> 7, k = idx & 127;
    BfC[idx] = f2h(W_h[(size_t)k*DDIM + n]);
  }
}

// ---- fused gemmA+gemmB, WAVE-AUTONOMOUS (R15): zero barriers in gemm path.
//      Each wave owns an 8 KB LDS slice; stages B in [64n][64k] swizzled chunks
//      (128 B rows -> all 32 banks) and consumes immediately (DS pipe is
//      per-wave in-order). 32 KB/block -> 16 waves/CU, no vmcnt(0) drains.
//      blocks < NPB: bucket partition with LOCAL bucket scan (R10-proven). ----
__global__ __launch_bounds__(256, 4) void gemmAB_k(
    const float* __restrict__ x, const ushort* __restrict__ BfA,
    const ushort* __restrict__ BfB, const float* __restrict__ b_in,
    ushort* __restrict__ gf,
    const float* __restrict__ vs, const float* __restrict__ vd,
    float* __restrict__ os, float* __restrict__ od,
    float* __restrict__ bms, float* __restrict__ bmd,
    const int* __restrict__ ei, const int* __restrict__ cpart, int* __restrict__ pairs,
    int* __restrict__ gmS)
{
  __shared__ __attribute__((aligned(16))) ushort Bs[4*4096];    // 32 KB: 8 KB per wave
  if (blockIdx.x < NPB){                           // partition, single sweep
    int* cur = (int*)Bs;                           // [256] cursors (aliases Bs)
    int* scn = ((int*)Bs) + NBUCK;                 // [256] scan scratch
    const int pb = blockIdx.x, t = threadIdx.x;
    int tot = 0, before = 0;
    #pragma unroll 8
    for (int i=0;i<NPB;i++){                       // coalesced column pass (pipelined)
      const int c = cpart[i*NBUCK + t];
      if (i < pb) before += c;                     // this block's intra-bucket offset
      tot += c;                                    // bucket total
    }
    scn[t] = tot;
    __syncthreads();
    #pragma unroll
    for (int off=1; off<NBUCK; off<<=1){           // Hillis-Steele inclusive scan
      int v = (t>=off) ? scn[t-off] : 0;
      __syncthreads();
      scn[t] += v;
      __syncthreads();
    }
    const int S = scn[t] - tot;                    // exclusive: bucket base S[t]
    cur[t] = S + before;                           // this block's write cursor
    if (pb == 0) gmS[t] = S;                       // bucket bases for fineagg_k
    __syncthreads();
    const int e0 = pb*CHP, e1 = min(NEDGE, e0+CHP);
    for (int e=e0+t; e<e1; e+=256){
      int dst = min(max(ei[NEDGE+e],0), NNODE-1);
      int src = min(max(ei[e],0), NNODE-1);
      int bk = (unsigned)dst / BSZ;
      int pos = atomicAdd(&cur[bk], 1);            // LDS atomic
      pairs[pos] = src | ((dst - bk*BSZ) << 16);
    }
    return;
  }
  const int lane = threadIdx.x & 63;
  const int wave = threadIdx.x >> 6;
  const int q = lane >> 4, c = lane & 15;
  const int tile = (blockIdx.x - NPB)*4 + wave;
  if (tile >= NTILES) return;                      // no barriers in this path: safe
  const int rowBase = tile*16;
  const int swz = (c&7)<<4;
  char* bw = (char*)Bs + wave*8192;                // wave-private 8 KB slice
  // A-fragments: x rows fp32, contiguous per lane (independent, in-flight)
  half8 af[8];
  {
    const float* __restrict__ ap = x + (size_t)(rowBase + c)*KDIN;
    #pragma unroll
    for (int s=0;s<7;s++){                         // k <= 223 < 239: no guard
      const float* __restrict__ p = ap + s*32 + q*8;
      #pragma unroll
      for (int i=0;i<8;i++) af[s][i] = (_Float16)p[i];
    }
    #pragma unroll
    for (int i=0;i<8;i++){                         // guarded tail (k = 224..255)
      const int k = 224 + q*8 + i;
      af[7][i] = (_Float16)((k < KDIN) ? ap[k] : 0.f);
    }
  }
  f32x4 acc[8];
  #pragma unroll
  for (int t=0;t<8;t++) acc[t] = (f32x4){0.f,0.f,0.f,0.f};
  // ---- phase A: 8 wave-private stages of [64 n][64 k] (8 KB each) ----
  #pragma unroll
  for (int s2=0; s2<4; ++s2){
    #pragma unroll
    for (int h=0; h<2; ++h){
      #pragma unroll
      for (int i=0;i<8;++i){                       // 512 chunks of 16 B
        const int j = i*64 + lane;
        const int nl = j>>3, kc = j&7;
        const half8 v = *(const half8*)(BfA + (size_t)(h*64+nl)*256 + s2*64 + kc*8);
        *(half8*)(bw + nl*128 + ((kc*16) ^ ((nl&7)<<4))) = v;
      }
      #pragma unroll
      for (int sp=0; sp<2; ++sp){
        #pragma unroll
        for (int t=0;t<4;++t){
          const int rl = 16*t + c;                 // rl&7 == c&7
          const half8 bf = *(const half8*)(bw + rl*128 + ((sp*64 + q*16) ^ swz));
          acc[h*4+t] = __builtin_amdgcn_mfma_f32_16x16x32_f16(af[s2*2+sp], bf, acc[h*4+t], 0,0,0);
        }
      }
    }
  }
  // epilogue A: h = leaky(acc + b_in) -> wave-private swizzled h tile (4 KB)
  #pragma unroll
  for (int t=0;t<8;t++){
    const int col = 16*t + c;
    const float bv = b_in[col];
    #pragma unroll
    for (int r=0;r<4;r++){
      const int row = q*4 + r;
      float v = acc[t][r] + bv;
      v = (v >= 0.f) ? v : 0.01f*v;
      *(_Float16*)(bw + ((row*256 + col*2) ^ ((row&7)<<4))) = (_Float16)v;
    }
  }
  // af2 from h tile (registers) BEFORE BfB staging clobbers the slice
  half8 af2[4];
  #pragma unroll
  for (int s=0;s<4;s++) af2[s] = *(const half8*)(bw + c*256 + ((s*64 + q*16) ^ swz));
  #pragma unroll
  for (int t=0;t<8;t++) acc[t] = (f32x4){0.f,0.f,0.f,0.f};
  // ---- phase B: 4 wave-private stages of [64 n][64 k] from BfB ----
  #pragma unroll
  for (int h2=0; h2<2; ++h2){
    #pragma unroll
    for (int k2=0; k2<2; ++k2){
      #pragma unroll
      for (int i=0;i<8;++i){
        const int j = i*64 + lane;
        const int nl = j>>3, kc = j&7;
        const half8 v = *(const half8*)(BfB + (size_t)(h2*64+nl)*128 + k2*64 + kc*8);
        *(half8*)(bw + nl*128 + ((kc*16) ^ ((nl&7)<<4))) = v;
      }
      #pragma unroll
      for (int sp=0; sp<2; ++sp){
        #pragma unroll
        for (int t=0;t<4;++t){
          const int rl = 16*t + c;
          const half8 bf = *(const half8*)(bw + rl*128 + ((sp*64 + q*16) ^ swz));
          acc[h2*4+t] = __builtin_amdgcn_mfma_f32_16x16x32_f16(af2[k2*2+sp], bf, acc[h2*4+t], 0,0,0);
        }
      }
    }
  }
  // epilogue B: gf f16 + row dots (a_src/a_dst) + per-tile maxes
  float pr0[4] = {0,0,0,0}, pr1[4] = {0,0,0,0};
  #pragma unroll
  for (int t=0;t<8;t++){
    const int col = 16*t + c;
    const float va = vs[col], vb = vd[col];
    #pragma unroll
    for (int r=0;r<4;r++){
      const int row = rowBase + q*4 + r;
      const float v = acc[t][r];
      gf[(size_t)row*DDIM + col] = f2h(v);
      pr0[r] += v*va; pr1[r] += v*vb;
    }
  }
  float lmax_s = -3.0e38f, lmax_d = -3.0e38f;
  #pragma unroll
  for (int r=0;r<4;r++){
    float s0 = pr0[r], s1 = pr1[r];
    s0 += __shfl_xor(s0,8); s1 += __shfl_xor(s1,8);
    s0 += __shfl_xor(s0,4); s1 += __shfl_xor(s1,4);
    s0 += __shfl_xor(s0,2); s1 += __shfl_xor(s1,2);
    s0 += __shfl_xor(s0,1); s1 += __shfl_xor(s1,1);
    lmax_s = fmaxf(lmax_s, s0); lmax_d = fmaxf(lmax_d, s1);
    if (c == 0){
      const int row = rowBase + q*4 + r;
      os[row] = s0; od[row] = s1;
    }
  }
  #pragma unroll
  for (int off=32; off>0; off>>=1){
    lmax_s = fmaxf(lmax_s, __shfl_xor(lmax_s, off));
    lmax_d = fmaxf(lmax_d, __shfl_xor(lmax_d, off));
  }
  if (lane == 0){ bms[tile] = lmax_s; bmd[tile] = lmax_d; }
}

// ---- fused fine-CSR + softmax-gather: TWO blocks per bucket (R12-proven). ----
__global__ __launch_bounds__(1024, 2) void fineagg_k(
    const int* __restrict__ pairs, const int* __restrict__ gmS,
    int* __restrict__ es, const ushort* __restrict__ gf,
    const float* __restrict__ a_src, const float* __restrict__ a_dst,
    const float* __restrict__ bms, const float* __restrict__ bmd,
    const float* __restrict__ b_gat, ushort* __restrict__ og)
{
  __shared__ int fh[256];
  __shared__ int sc2[256];
  __shared__ int offL[256];
  __shared__ int degL[256];
  __shared__ int esL[ESCAP];
  __shared__ float Msh;
  const int b = blockIdx.x >> 1;                   // bucket
  const int hf2 = blockIdx.x & 1;                  // which half of the dsts
  const int t = threadIdx.x;
  float ms = -3.0e38f, md = -3.0e38f;
  for (int i=t; i<NTILES; i+=1024){ ms = fmaxf(ms, bms[i]); md = fmaxf(md, bmd[i]); }
  #pragma unroll
  for (int off=32; off>0; off>>=1){
    ms = fmaxf(ms, __shfl_xor(ms, off));
    md = fmaxf(md, __shfl_xor(md, off));
  }
  float* red = (float*)sc2;                        // reuse pre-scan
  const int w = t >> 6;                            // wave 0..15
  if ((t & 63) == 0){ red[w] = ms; red[16+w] = md; }
  __syncthreads();
  if (t == 0){
    float As = red[0], Ad = red[16];
    #pragma unroll
    for (int i=1;i<16;i++){ As = fmaxf(As, red[i]); Ad = fmaxf(Ad, red[16+i]); }
    float M = As + Ad;
    Msh = (M >= 0.f) ? M : 0.2f*M;
  }
  if (t < 256) fh[t] = 0;
  __syncthreads();                                 // Msh done; red free; fh zeroed
  const int s0 = gmS[b];
  const int s1 = (b < NBUCK-1) ? gmS[b+1] : NEDGE;
  const bool fit = (s1 - s0) <= ESCAP;             // data-independent fallback
  for (int i=s0+t; i<s1; i+=1024)                  // contiguous, L2-hot
    atomicAdd(&fh[pairs[i] >> 16], 1);
  __syncthreads();
  int deg = 0;
  if (t < 256){ deg = fh[t]; sc2[t] = deg; }
  __syncthreads();
  #pragma unroll
  for (int off=1; off<256; off<<=1){               // inclusive scan (threads 0..255)
    int v = (t < 256 && t >= off) ? sc2[t-off] : 0;
    __syncthreads();
    if (t < 256) sc2[t] += v;
    __syncthreads();
  }
  if (t < 256){
    const int excl = sc2[t] - deg;
    offL[t] = excl;                                // local (in-bucket) offset
    degL[t] = deg;
    fh[t] = excl;                                  // becomes cursor
  }
  __syncthreads();
  for (int i=s0+t; i<s1; i+=1024){                 // scatter into LDS CSR
    const int p = pairs[i];
    const int pos = atomicAdd(&fh[p >> 16], 1);
    if (fit) esL[pos] = p & 0xFFFF;
    else if (hf2 == 0) es[s0 + pos] = p & 0xFFFF;  // only one half writes fallback
  }
  __syncthreads();
  const float M = Msh;
  const int lane = t & 63;
  const int half = lane >> 5, li = lane & 31;
  const int slot = (t >> 6)*2 + half;              // 0..31
  const int D0 = hf2*HBSZ, D1 = hf2 ? BSZ : HBSZ;
  const float4 bg = *(const float4*)&b_gat[li*4];
  for (int d = D0 + slot; d < D1; d += 32){
    const int dst = b*BSZ + d;
    if (dst >= NNODE) continue;
    const float ad = a_dst[dst];
    f32x4 a0={0,0,0,0}, a1={0,0,0,0}, a2={0,0,0,0}, a3={0,0,0,0};
    float w0s=0.f, w1s=0.f, w2s=0.f, w3s=0.f;
    if (fit){
      const int start = offL[d];
      const int dg = degL[d];
      const int* __restrict__ bin = esL + start;
      int j = 0;
      for (; j+3 < dg; j += 4){
        const int i0=bin[j], i1=bin[j+1], i2=bin[j+2], i3=bin[j+3];
        float e0=a_src[i0]+ad; e0=(e0>=0.f)?e0:0.2f*e0;
        float e1=a_src[i1]+ad; e1=(e1>=0.f)?e1:0.2f*e1;
        float e2=a_src[i2]+ad; e2=(e2>=0.f)?e2:0.2f*e2;
        float e3=a_src[i3]+ad; e3=(e3>=0.f)?e3:0.2f*e3;
        const float w0=__expf(e0-M), w1=__expf(e1-M), w2=__expf(e2-M), w3=__expf(e3-M);
        const half4 g0 = *(const half4*)(gf + (size_t)i0*DDIM + li*4);
        const half4 g1 = *(const half4*)(gf + (size_t)i1*DDIM + li*4);
        const half4 g2 = *(const half4*)(gf + (size_t)i2*DDIM + li*4);
        const half4 g3 = *(const half4*)(gf + (size_t)i3*DDIM + li*4);
        #pragma unroll
        for (int i=0;i<4;i++){
          a0[i] += w0*(float)g0[i]; a1[i] += w1*(float)g1[i];
          a2[i] += w2*(float)g2[i]; a3[i] += w3*(float)g3[i];
        }
        w0s += w0; w1s += w1; w2s += w2; w3s += w3;
      }
      for (; j < dg; ++j){
        const int si = bin[j];
        float e0=a_src[si]+ad; e0=(e0>=0.f)?e0:0.2f*e0;
        const float w2v = __expf(e0-M);
        const half4 gv = *(const half4*)(gf + (size_t)si*DDIM + li*4);
        #pragma unroll
        for (int i=0;i<4;i++) a0[i] += w2v*(float)gv[i];
        w0s += w2v;
      }
    } else {                                       // overflow slow path (~never)
      for (int i=s0; i<s1; ++i){
        const int p = pairs[i];
        if ((p >> 16) != d) continue;
        const int si = p & 0xFFFF;
        float e0=a_src[si]+ad; e0=(e0>=0.f)?e0:0.2f*e0;
        const float w2v = __expf(e0-M);
        const half4 gv = *(const half4*)(gf + (size_t)si*DDIM + li*4);
        #pragma unroll
        for (int i2v=0;i2v<4;i2v++) a0[i2v] += w2v*(float)gv[i2v];
        w0s += w2v;
      }
    }
    {                                              // self-loop (unconditional)
      float evs=a_src[dst]+ad; evs=(evs>=0.f)?evs:0.2f*evs;
      const float w2v = __expf(evs-M);
      const half4 gv = *(const half4*)(gf + (size_t)dst*DDIM + li*4);
      #pragma unroll
      for (int i=0;i<4;i++) a0[i] += w2v*(float)gv[i];
      w0s += w2v;
    }
    const float inv = 1.f/(w0s+w1s+w2s+w3s);       // >= w_self > 0
    ushort4 o;
    o.x = f2h((a0[0]+a1[0]+a2[0]+a3[0])*inv + bg.x);
    o.y = f2h((a0[1]+a1[1]+a2[1]+a3[1])*inv + bg.y);
    o.z = f2h((a0[2]+a1[2]+a2[2]+a3[2])*inv + bg.z);
    o.w = f2h((a0[3]+a1[3]+a2[3]+a3[3])*inv + bg.w);
    *(ushort4*)(og + (size_t)dst*DDIM + li*4) = o;
  }
}

// ---- gemmC: y = leaky(og@W_h + b_h) @ W_out + b_out -> fp32 out ----
__global__ __launch_bounds__(256, 4) void gemmC_k(
    const ushort* __restrict__ Af, const ushort* __restrict__ Btf,
    const float* __restrict__ bias, float* __restrict__ outf,
    const float* __restrict__ Wo, const float* __restrict__ bo)
{
  constexpr int Kpad = 128, Kb = 256;
  __shared__ __attribute__((aligned(16))) ushort Bs[128*Kpad];  // 32 KB
  #pragma unroll
  for (int it=0; it<8; ++it){
    const int idx = it*256 + threadIdx.x;
    const int row = idx >> 4, sl = (idx & 15)*16;
    const half8 v = *(const half8*)(Btf + (size_t)idx*8);
    *(half8*)((char*)Bs + row*Kb + (sl ^ ((row&7)<<4))) = v;
  }
  __syncthreads();
  const int lane = threadIdx.x & 63;
  const int wave = threadIdx.x >> 6;
  const int q = lane >> 4, c = lane & 15;
  const int tile = blockIdx.x*4 + wave;
  if (tile >= NTILES) return;
  const int rowBase = tile*16;
  half8 af[4];
  const ushort* __restrict__ ap = Af + (size_t)(rowBase + c)*Kpad + q*8;
  #pragma unroll
  for (int s=0;s<4;s++) af[s] = *(const half8*)(ap + s*32);
  f32x4 acc[8];
  #pragma unroll
  for (int t=0;t<8;t++) acc[t] = (f32x4){0.f,0.f,0.f,0.f};
  const int swz = (c&7)<<4;
  const char* __restrict__ bsl = (const char*)Bs + c*Kb;
  #pragma unroll
  for (int s=0;s<4;s++){
    const int so = (s*64 + q*16) ^ swz;
    #pragma unroll
    for (int t=0;t<8;t++){
      const half8 bf = *(const half8*)(bsl + t*16*Kb + so);
      acc[t] = __builtin_amdgcn_mfma_f32_16x16x32_f16(af[s], bf, acc[t], 0,0,0);
    }
  }
  float pr0[4] = {0,0,0,0}, pr1[4] = {0,0,0,0};
  #pragma unroll
  for (int t=0;t<8;t++){
    const int col = 16*t + c;
    const float bv = bias[col];
    const float va = Wo[2*col], vb = Wo[2*col+1];
    #pragma unroll
    for (int r=0;r<4;r++){
      float v = acc[t][r] + bv;
      v = (v >= 0.f) ? v : 0.01f*v;
      pr0[r] += v*va; pr1[r] += v*vb;
    }
  }
  #pragma unroll
  for (int r=0;r<4;r++){
    float s0 = pr0[r], s1 = pr1[r];
    s0 += __shfl_xor(s0,8); s1 += __shfl_xor(s1,8);
    s0 += __shfl_xor(s0,4); s1 += __shfl_xor(s1,4);
    s0 += __shfl_xor(s0,2); s1 += __shfl_xor(s1,2);
    s0 += __shfl_xor(s0,1); s1 += __shfl_xor(s1,1);
    if (c == 0){
      const int row = rowBase + q*4 + r;
      float2 y2; y2.x = s0 + bo[0]; y2.y = s1 + bo[1];
      *(float2*)&outf[(size_t)row*2] = y2;
    }
  }
}

extern "C" void kernel_launch(void* const* d_in, const int* in_sizes, int n_in,
                              void* d_out, int out_size, void* d_ws, size_t ws_size,
                              hipStream_t stream)
{
  const float* x       = (const float*)d_in[0];
  const int*   ei      = (const int*)d_in[1];
  // d_in[2] = edge_type (unused by reference)
  const float* W_in    = (const float*)d_in[3];
  const float* b_in    = (const float*)d_in[4];
  const float* W_gat   = (const float*)d_in[5];
  const float* att_src = (const float*)d_in[6];
  const float* att_dst = (const float*)d_in[7];
  const float* b_gat   = (const float*)d_in[8];
  const float* W_h     = (const float*)d_in[9];
  const float* b_h     = (const float*)d_in[10];
  const float* W_out   = (const float*)d_in[11];
  const float* b_out   = (const float*)d_in[12];

  // workspace (~33 MB):
  char* ws = (char*)d_ws;
  ushort*   gf     = (ushort*)  (ws + 0);          // g f16 [N,128]    12.8 MB
  ushort*   og     = (ushort*)  (ws + 12800000);   // og f16 [N,128]   12.8 MB
  ushort*   BfA    = (ushort*)  (ws + 25600000);   // 128 KB
  ushort*   BfB    = (ushort*)  (ws + 25800000);   // 32 KB
  ushort*   BfC    = (ushort*)  (ws + 25900000);   // 32 KB
  int*      cpart  = (int*)     (ws + 26000000);   // [NPB][256] counts, 128 KB
  int*      pairs  = (int*)     (ws + 26300000);   // bucket-major packed edges, 2.4 MB
  int*      es     = (int*)     (ws + 28700000);   // CSR src fallback, 2.4 MB
  float*    a_src  = (float*)   (ws + 31100000);   // 200 KB
  float*    a_dst  = (float*)   (ws + 31300000);   // 200 KB
  int*      gmS    = (int*)     (ws + 31500000);   // bucket bases S[256], 1 KB
  float*    bmaxS  = (float*)   (ws + 31600000);   // per-tile maxes, 12.5 KB
  float*    bmaxD  = (float*)   (ws + 31616000);   // 12.5 KB

  // 1: coarse histogram (block-major counts) || weight transposes
  pre_k<<<NPB + 256, 256, 0, stream>>>(W_in, W_gat, W_h, BfA, BfB, BfC, ei, cpart);
  // 2: fused gemmA+gemmB (wave-autonomous, barrier-free) || bucket partition
  gemmAB_k<<<NPB + NBG, 256, 0, stream>>>(x, BfA, BfB, b_in, gf,
      att_src, att_dst, a_src, a_dst, bmaxS, bmaxD, ei, cpart, pairs, gmS);
  // 3: fused fine-CSR + softmax-gather, 2 blocks/bucket (512 blocks -> all CUs)
  fineagg_k<<<2*NBUCK, 1024, 0, stream>>>(pairs, gmS, es, gf, a_src, a_dst,
      bmaxS, bmaxD, b_gat, og);
  // 4: gemmC
  gemmC_k<<<NBG, 256, 0, stream>>>(og, BfC, b_h, (float*)d_out, W_out, b_out);
}

// Round 16
// 166.075 us; speedup vs baseline: 1.0918x; 1.0918x over previous
//
#include <hip/hip_runtime.h>

#define NNODE 50000
#define NEDGE 600000
#define KDIN  239
#define DDIM  128
#define NTILES 3125           // 3125*16 == 50000 exactly
#define NBG   782             // one-shot gemm blocks: 782*4 waves >= 3125 tiles
#define NBUCK 256             // coarse dst buckets
#define BSZ   196             // dsts per bucket (196*256 >= 50000)
#define HBSZ  98              // dsts per fineagg half-block (BSZ/2)
#define NPB   128             // partition/hist blocks
#define CHP   4688            // edges per hist/partition block (128*4688 >= 600000)
#define ESCAP 4096            // LDS CSR capacity per bucket (global fallback if exceeded)

typedef _Float16 half8 __attribute__((ext_vector_type(8)));
typedef _Float16 half4 __attribute__((ext_vector_type(4)));
typedef __attribute__((ext_vector_type(4))) float f32x4;

__device__ __forceinline__ ushort f2h(float f){
  union { _Float16 h; ushort u; } c; c.h = (_Float16)f; return c.u;
}

// ---- prologue: coarse LDS histogram (block-major cpart counts) || weight transposes ----
__global__ __launch_bounds__(256) void pre_k(
    const float* __restrict__ W_in, const float* __restrict__ W_gat, const float* __restrict__ W_h,
    ushort* __restrict__ BfA, ushort* __restrict__ BfB, ushort* __restrict__ BfC,
    const int* __restrict__ ei, int* __restrict__ cpart)
{
  __shared__ int hb[NBUCK];
  const int b = blockIdx.x, t = threadIdx.x;
  if (b < NPB){                                    // coarse histogram, single sweep
    hb[t] = 0;
    __syncthreads();
    const int e0 = b*CHP, e1 = min(NEDGE, e0+CHP);
    for (int e=e0+t; e<e1; e+=256){
      int dst = min(max(ei[NEDGE+e],0), NNODE-1);
      atomicAdd(&hb[dst/BSZ], 1);                  // LDS atomic, 256 bins
    }
    __syncthreads();
    cpart[b*NBUCK + t] = hb[t];                    // block-major: coalesced write
  } else if (b < NPB + 128){                       // W_in [239,128] -> BfA[n=128][k=256]
    int idx = (b-NPB)*256 + t; int n = idx >> 8, k = idx & 255;
    BfA[idx] = (k < KDIN) ? f2h(W_in[(size_t)k*DDIM + n]) : (ushort)0;
  } else if (b < NPB + 192){                       // W_gat -> BfB[n][128]
    int idx = (b-NPB-128)*256 + t; int n = idx >> 7, k = idx & 127;
    BfB[idx] = f2h(W_gat[(size_t)k*DDIM + n]);
  } else {                                         // W_h -> BfC[n][128]
    int idx = (b-NPB-192)*256 + t; int n = idx >> 7, k = idx & 127;
    BfC[idx] = f2h(W_h[(size_t)k*DDIM + n]);
  }
}

// ---- fused gemmA+gemmB, 48 KB LDS (3 blocks/CU): B staged in two 32 KB K-halves.
//      blocks < NPB: bucket partition with LOCAL bucket scan (R10-proven). ----
__global__ __launch_bounds__(256, 3) void gemmAB_k(
    const float* __restrict__ x, const ushort* __restrict__ BfA,
    const ushort* __restrict__ BfB, const float* __restrict__ b_in,
    ushort* __restrict__ gf,
    const float* __restrict__ vs, const float* __restrict__ vd,
    float* __restrict__ os, float* __restrict__ od,
    float* __restrict__ bms, float* __restrict__ bmd,
    const int* __restrict__ ei, const int* __restrict__ cpart, int* __restrict__ pairs,
    int* __restrict__ gmS)
{
  __shared__ __attribute__((aligned(16))) ushort Bs[128*128];   // 32 KB (half-K / BfB)
  __shared__ __attribute__((aligned(16))) ushort ht[4][16*128]; // 16 KB: per-wave h tile
  if (blockIdx.x < NPB){                           // partition, single sweep
    int* cur = (int*)Bs;                           // [256] cursors (aliases Bs)
    int* scn = ((int*)Bs) + NBUCK;                 // [256] scan scratch
    const int pb = blockIdx.x, t = threadIdx.x;
    int tot = 0, before = 0;
    #pragma unroll 8
    for (int i=0;i<NPB;i++){                       // coalesced column pass (pipelined)
      const int c = cpart[i*NBUCK + t];
      if (i < pb) before += c;                     // this block's intra-bucket offset
      tot += c;                                    // bucket total
    }
    scn[t] = tot;
    __syncthreads();
    #pragma unroll
    for (int off=1; off<NBUCK; off<<=1){           // Hillis-Steele inclusive scan
      int v = (t>=off) ? scn[t-off] : 0;
      __syncthreads();
      scn[t] += v;
      __syncthreads();
    }
    const int S = scn[t] - tot;                    // exclusive: bucket base S[t]
    cur[t] = S + before;                           // this block's write cursor
    if (pb == 0) gmS[t] = S;                       // bucket bases for fineagg_k
    __syncthreads();
    const int e0 = pb*CHP, e1 = min(NEDGE, e0+CHP);
    for (int e=e0+t; e<e1; e+=256){
      int dst = min(max(ei[NEDGE+e],0), NNODE-1);
      int src = min(max(ei[e],0), NNODE-1);
      int bk = (unsigned)dst / BSZ;
      int pos = atomicAdd(&cur[bk], 1);            // LDS atomic
      pairs[pos] = src | ((dst - bk*BSZ) << 16);
    }
    return;
  }
  const int lane = threadIdx.x & 63;
  const int wave = threadIdx.x >> 6;
  const int q = lane >> 4, c = lane & 15;
  const int tile = (blockIdx.x - NPB)*4 + wave;
  const bool act = tile < NTILES;
  const int rowBase = tile*16;
  const int swz = (c&7)<<4;
  f32x4 acc[8];
  half8 af[8];
  if (act){
    // A-fragments: x rows fp32, contiguous per lane (independent, in-flight)
    const float* __restrict__ ap = x + (size_t)(rowBase + c)*KDIN;
    #pragma unroll
    for (int s=0;s<7;s++){                         // k <= 223 < 239: no guard
      const float* __restrict__ p = ap + s*32 + q*8;
      #pragma unroll
      for (int i=0;i<8;i++) af[s][i] = (_Float16)p[i];
    }
    #pragma unroll
    for (int i=0;i<8;i++){                         // guarded tail (k = 224..255)
      const int k = 224 + q*8 + i;
      af[7][i] = (_Float16)((k < KDIN) ? ap[k] : 0.f);
    }
    #pragma unroll
    for (int t=0;t<8;t++) acc[t] = (f32x4){0.f,0.f,0.f,0.f};
  }
  // ---- phase A in two K-halves: stage 32 KB of BfA, MFMA 4 steps, repeat ----
  #pragma unroll
  for (int H=0; H<2; ++H){
    #pragma unroll
    for (int it=0; it<8; ++it){                    // 2048 16B chunks: [128][128] half
      const int idx = it*256 + threadIdx.x;
      const int row = idx >> 4, sl = (idx & 15)*16;
      const half8 v = *(const half8*)(BfA + (size_t)row*256 + H*128 + (idx & 15)*8);
      *(half8*)((char*)Bs + row*256 + (sl ^ ((row&7)<<4))) = v;
    }
    __syncthreads();
    if (act){
      const char* __restrict__ bsl = (const char*)Bs + c*256;
      #pragma unroll
      for (int s=0;s<4;s++){
        const int so = (s*64 + q*16) ^ swz;
        #pragma unroll
        for (int t=0;t<8;t++){
          const half8 bf = *(const half8*)(bsl + t*16*256 + so);
          acc[t] = __builtin_amdgcn_mfma_f32_16x16x32_f16(af[H*4+s], bf, acc[t], 0,0,0);
        }
      }
    }
    __syncthreads();                               // half consumed; safe to overwrite
  }
  if (act){
    // epilogue A -> swizzled LDS h tile (wave-private 4 KB)
    char* __restrict__ hw = (char*)&ht[wave][0];
    #pragma unroll
    for (int t=0;t<8;t++){
      const int col = 16*t + c;
      const float bv = b_in[col];
      #pragma unroll
      for (int r=0;r<4;r++){
        const int row = q*4 + r;
        float v = acc[t][r] + bv;
        v = (v >= 0.f) ? v : 0.01f*v;
        *(_Float16*)(hw + ((row*256 + col*2) ^ ((row&7)<<4))) = (_Float16)v;
      }
    }
  }
  // stage BfB [128][128] f16 -> Bs, same swizzle; Kb=256
  #pragma unroll
  for (int it=0; it<8; ++it){
    const int idx = it*256 + threadIdx.x;          // 2048 16B chunks
    const int row = idx >> 4, sl = (idx & 15)*16;
    const half8 v = *(const half8*)(BfB + (size_t)idx*8);
    *(half8*)((char*)Bs + row*256 + (sl ^ ((row&7)<<4))) = v;
  }
  __syncthreads();
  if (!act) return;                                // no barriers past this point
  // ---- phase B: g = h@W_gat; A-frags from ht (same swizzle) ----
  half8 af2[4];
  const char* __restrict__ hr = (const char*)&ht[wave][0] + c*256;
  #pragma unroll
  for (int s=0;s<4;s++) af2[s] = *(const half8*)(hr + ((s*64 + q*16) ^ swz));
  #pragma unroll
  for (int t=0;t<8;t++) acc[t] = (f32x4){0.f,0.f,0.f,0.f};
  const char* __restrict__ bsl2 = (const char*)Bs + c*256;
  #pragma unroll
  for (int s=0;s<4;s++){
    const int so = (s*64 + q*16) ^ swz;
    #pragma unroll
    for (int t=0;t<8;t++){
      const half8 bf = *(const half8*)(bsl2 + t*16*256 + so);
      acc[t] = __builtin_amdgcn_mfma_f32_16x16x32_f16(af2[s], bf, acc[t], 0,0,0);
    }
  }
  // epilogue B: gf f16 + row dots (a_src/a_dst) + per-tile maxes
  float pr0[4] = {0,0,0,0}, pr1[4] = {0,0,0,0};
  #pragma unroll
  for (int t=0;t<8;t++){
    const int col = 16*t + c;
    const float va = vs[col], vb = vd[col];
    #pragma unroll
    for (int r=0;r<4;r++){
      const int row = rowBase + q*4 + r;
      const float v = acc[t][r];
      gf[(size_t)row*DDIM + col] = f2h(v);
      pr0[r] += v*va; pr1[r] += v*vb;
    }
  }
  float lmax_s = -3.0e38f, lmax_d = -3.0e38f;
  #pragma unroll
  for (int r=0;r<4;r++){
    float s0 = pr0[r], s1 = pr1[r];
    s0 += __shfl_xor(s0,8); s1 += __shfl_xor(s1,8);
    s0 += __shfl_xor(s0,4); s1 += __shfl_xor(s1,4);
    s0 += __shfl_xor(s0,2); s1 += __shfl_xor(s1,2);
    s0 += __shfl_xor(s0,1); s1 += __shfl_xor(s1,1);
    lmax_s = fmaxf(lmax_s, s0); lmax_d = fmaxf(lmax_d, s1);
    if (c == 0){
      const int row = rowBase + q*4 + r;
      os[row] = s0; od[row] = s1;
    }
  }
  #pragma unroll
  for (int off=32; off>0; off>>=1){
    lmax_s = fmaxf(lmax_s, __shfl_xor(lmax_s, off));
    lmax_d = fmaxf(lmax_d, __shfl_xor(lmax_d, off));
  }
  if (lane == 0){ bms[tile] = lmax_s; bmd[tile] = lmax_d; }
}

// ---- fused fine-CSR + softmax-gather: TWO blocks per bucket (R12-proven).
//      Each half-block duplicates the cheap CSR build (LDS-local), then
//      aggregates HALF the dsts -> 512 blocks @ 2/CU fills all 256 CUs. ----
__global__ __launch_bounds__(1024, 2) void fineagg_k(
    const int* __restrict__ pairs, const int* __restrict__ gmS,
    int* __restrict__ es, const ushort* __restrict__ gf,
    const float* __restrict__ a_src, const float* __restrict__ a_dst,
    const float* __restrict__ bms, const float* __restrict__ bmd,
    const float* __restrict__ b_gat, ushort* __restrict__ og)
{
  __shared__ int fh[256];
  __shared__ int sc2[256];
  __shared__ int offL[256];
  __shared__ int degL[256];
  __shared__ int esL[ESCAP];
  __shared__ float Msh;
  const int b = blockIdx.x >> 1;                   // bucket
  const int hf2 = blockIdx.x & 1;                  // which half of the dsts
  const int t = threadIdx.x;
  // ---- global max (redundant per block; 6250 L2-hot floats x2) ----
  float ms = -3.0e38f, md = -3.0e38f;
  for (int i=t; i<NTILES; i+=1024){ ms = fmaxf(ms, bms[i]); md = fmaxf(md, bmd[i]); }
  #pragma unroll
  for (int off=32; off>0; off>>=1){
    ms = fmaxf(ms, __shfl_xor(ms, off));
    md = fmaxf(md, __shfl_xor(md, off));
  }
  float* red = (float*)sc2;                        // reuse pre-scan
  const int w = t >> 6;                            // wave 0..15
  if ((t & 63) == 0){ red[w] = ms; red[16+w] = md; }
  __syncthreads();
  if (t == 0){
    float As = red[0], Ad = red[16];
    #pragma unroll
    for (int i=1;i<16;i++){ As = fmaxf(As, red[i]); Ad = fmaxf(Ad, red[16+i]); }
    float M = As + Ad;
    Msh = (M >= 0.f) ? M : 0.2f*M;
  }
  if (t < 256) fh[t] = 0;
  __syncthreads();                                 // Msh done; red free; fh zeroed
  // ---- fine CSR: hist -> scan -> scatter (duplicated per half-block) ----
  const int s0 = gmS[b];
  const int s1 = (b < NBUCK-1) ? gmS[b+1] : NEDGE;
  const bool fit = (s1 - s0) <= ESCAP;             // data-independent fallback
  for (int i=s0+t; i<s1; i+=1024)                  // contiguous, L2-hot
    atomicAdd(&fh[pairs[i] >> 16], 1);
  __syncthreads();
  int deg = 0;
  if (t < 256){ deg = fh[t]; sc2[t] = deg; }
  __syncthreads();
  #pragma unroll
  for (int off=1; off<256; off<<=1){               // inclusive scan (threads 0..255)
    int v = (t < 256 && t >= off) ? sc2[t-off] : 0;
    __syncthreads();
    if (t < 256) sc2[t] += v;
    __syncthreads();
  }
  if (t < 256){
    const int excl = sc2[t] - deg;
    offL[t] = excl;                                // local (in-bucket) offset
    degL[t] = deg;
    fh[t] = excl;                                  // becomes cursor
  }
  __syncthreads();
  for (int i=s0+t; i<s1; i+=1024){                 // scatter into LDS CSR
    const int p = pairs[i];
    const int pos = atomicAdd(&fh[p >> 16], 1);
    if (fit) esL[pos] = p & 0xFFFF;
    else if (hf2 == 0) es[s0 + pos] = p & 0xFFFF;  // only one half writes fallback
  }
  __syncthreads();
  // ---- aggregation: 32 dst-slots x 32 lanes; this block does dsts [D0,D1) ----
  const float M = Msh;
  const int lane = t & 63;
  const int half = lane >> 5, li = lane & 31;
  const int slot = (t >> 6)*2 + half;              // 0..31
  const int D0 = hf2*HBSZ, D1 = hf2 ? BSZ : HBSZ;
  const float4 bg = *(const float4*)&b_gat[li*4];
  for (int d = D0 + slot; d < D1; d += 32){
    const int dst = b*BSZ + d;
    if (dst >= NNODE) continue;
    const float ad = a_dst[dst];
    f32x4 a0={0,0,0,0}, a1={0,0,0,0}, a2={0,0,0,0}, a3={0,0,0,0};
    float w0s=0.f, w1s=0.f, w2s=0.f, w3s=0.f;
    if (fit){
      const int start = offL[d];
      const int dg = degL[d];
      const int* __restrict__ bin = esL + start;
      int j = 0;
      for (; j+3 < dg; j += 4){
        const int i0=bin[j], i1=bin[j+1], i2=bin[j+2], i3=bin[j+3];
        float e0=a_src[i0]+ad; e0=(e0>=0.f)?e0:0.2f*e0;
        float e1=a_src[i1]+ad; e1=(e1>=0.f)?e1:0.2f*e1;
        float e2=a_src[i2]+ad; e2=(e2>=0.f)?e2:0.2f*e2;
        float e3=a_src[i3]+ad; e3=(e3>=0.f)?e3:0.2f*e3;
        const float w0=__expf(e0-M), w1=__expf(e1-M), w2=__expf(e2-M), w3=__expf(e3-M);
        const half4 g0 = *(const half4*)(gf + (size_t)i0*DDIM + li*4);
        const half4 g1 = *(const half4*)(gf + (size_t)i1*DDIM + li*4);
        const half4 g2 = *(const half4*)(gf + (size_t)i2*DDIM + li*4);
        const half4 g3 = *(const half4*)(gf + (size_t)i3*DDIM + li*4);
        #pragma unroll
        for (int i=0;i<4;i++){
          a0[i] += w0*(float)g0[i]; a1[i] += w1*(float)g1[i];
          a2[i] += w2*(float)g2[i]; a3[i] += w3*(float)g3[i];
        }
        w0s += w0; w1s += w1; w2s += w2; w3s += w3;
      }
      for (; j < dg; ++j){
        const int si = bin[j];
        float e0=a_src[si]+ad; e0=(e0>=0.f)?e0:0.2f*e0;
        const float w2v = __expf(e0-M);
        const half4 gv = *(const half4*)(gf + (size_t)si*DDIM + li*4);
        #pragma unroll
        for (int i=0;i<4;i++) a0[i] += w2v*(float)gv[i];
        w0s += w2v;
      }
    } else {                                       // overflow slow path (~never)
      for (int i=s0; i<s1; ++i){
        const int p = pairs[i];
        if ((p >> 16) != d) continue;
        const int si = p & 0xFFFF;
        float e0=a_src[si]+ad; e0=(e0>=0.f)?e0:0.2f*e0;
        const float w2v = __expf(e0-M);
        const half4 gv = *(const half4*)(gf + (size_t)si*DDIM + li*4);
        #pragma unroll
        for (int i2v=0;i2v<4;i2v++) a0[i2v] += w2v*(float)gv[i2v];
        w0s += w2v;
      }
    }
    {                                              // self-loop (unconditional)
      float evs=a_src[dst]+ad; evs=(evs>=0.f)?evs:0.2f*evs;
      const float w2v = __expf(evs-M);
      const half4 gv = *(const half4*)(gf + (size_t)dst*DDIM + li*4);
      #pragma unroll
      for (int i=0;i<4;i++) a0[i] += w2v*(float)gv[i];
      w0s += w2v;
    }
    const float inv = 1.f/(w0s+w1s+w2s+w3s);       // >= w_self > 0
    ushort4 o;
    o.x = f2h((a0[0]+a1[0]+a2[0]+a3[0])*inv + bg.x);
    o.y = f2h((a0[1]+a1[1]+a2[1]+a3[1])*inv + bg.y);
    o.z = f2h((a0[2]+a1[2]+a2[2]+a3[2])*inv + bg.z);
    o.w = f2h((a0[3]+a1[3]+a2[3]+a3[3])*inv + bg.w);
    *(ushort4*)(og + (size_t)dst*DDIM + li*4) = o;
  }
}

// ---- gemmC: y = leaky(og@W_h + b_h) @ W_out + b_out -> fp32 out ----
__global__ __launch_bounds__(256, 4) void gemmC_k(
    const ushort* __restrict__ Af, const ushort* __restrict__ Btf,
    const float* __restrict__ bias, float* __restrict__ outf,
    const float* __restrict__ Wo, const float* __restrict__ bo)
{
  constexpr int Kpad = 128, Kb = 256;
  __shared__ __attribute__((aligned(16))) ushort Bs[128*Kpad];  // 32 KB
  #pragma unroll
  for (int it=0; it<8; ++it){
    const int idx = it*256 + threadIdx.x;
    const int row = idx >> 4, sl = (idx & 15)*16;
    const half8 v = *(const half8*)(Btf + (size_t)idx*8);
    *(half8*)((char*)Bs + row*Kb + (sl ^ ((row&7)<<4))) = v;
  }
  __syncthreads();
  const int lane = threadIdx.x & 63;
  const int wave = threadIdx.x >> 6;
  const int q = lane >> 4, c = lane & 15;
  const int tile = blockIdx.x*4 + wave;
  if (tile >= NTILES) return;
  const int rowBase = tile*16;
  half8 af[4];
  const ushort* __restrict__ ap = Af + (size_t)(rowBase + c)*Kpad + q*8;
  #pragma unroll
  for (int s=0;s<4;s++) af[s] = *(const half8*)(ap + s*32);
  f32x4 acc[8];
  #pragma unroll
  for (int t=0;t<8;t++) acc[t] = (f32x4){0.f,0.f,0.f,0.f};
  const int swz = (c&7)<<4;
  const char* __restrict__ bsl = (const char*)Bs + c*Kb;
  #pragma unroll
  for (int s=0;s<4;s++){
    const int so = (s*64 + q*16) ^ swz;
    #pragma unroll
    for (int t=0;t<8;t++){
      const half8 bf = *(const half8*)(bsl + t*16*Kb + so);
      acc[t] = __builtin_amdgcn_mfma_f32_16x16x32_f16(af[s], bf, acc[t], 0,0,0);
    }
  }
  float pr0[4] = {0,0,0,0}, pr1[4] = {0,0,0,0};
  #pragma unroll
  for (int t=0;t<8;t++){
    const int col = 16*t + c;
    const float bv = bias[col];
    const float va = Wo[2*col], vb = Wo[2*col+1];
    #pragma unroll
    for (int r=0;r<4;r++){
      float v = acc[t][r] + bv;
      v = (v >= 0.f) ? v : 0.01f*v;
      pr0[r] += v*va; pr1[r] += v*vb;
    }
  }
  #pragma unroll
  for (int r=0;r<4;r++){
    float s0 = pr0[r], s1 = pr1[r];
    s0 += __shfl_xor(s0,8); s1 += __shfl_xor(s1,8);
    s0 += __shfl_xor(s0,4); s1 += __shfl_xor(s1,4);
    s0 += __shfl_xor(s0,2); s1 += __shfl_xor(s1,2);
    s0 += __shfl_xor(s0,1); s1 += __shfl_xor(s1,1);
    if (c == 0){
      const int row = rowBase + q*4 + r;
      float2 y2; y2.x = s0 + bo[0]; y2.y = s1 + bo[1];
      *(float2*)&outf[(size_t)row*2] = y2;
    }
  }
}

extern "C" void kernel_launch(void* const* d_in, const int* in_sizes, int n_in,
                              void* d_out, int out_size, void* d_ws, size_t ws_size,
                              hipStream_t stream)
{
  const float* x       = (const float*)d_in[0];
  const int*   ei      = (const int*)d_in[1];
  // d_in[2] = edge_type (unused by reference)
  const float* W_in    = (const float*)d_in[3];
  const float* b_in    = (const float*)d_in[4];
  const float* W_gat   = (const float*)d_in[5];
  const float* att_src = (const float*)d_in[6];
  const float* att_dst = (const float*)d_in[7];
  const float* b_gat   = (const float*)d_in[8];
  const float* W_h     = (const float*)d_in[9];
  const float* b_h     = (const float*)d_in[10];
  const float* W_out   = (const float*)d_in[11];
  const float* b_out   = (const float*)d_in[12];

  // workspace (~33 MB):
  char* ws = (char*)d_ws;
  ushort*   gf     = (ushort*)  (ws + 0);          // g f16 [N,128]    12.8 MB
  ushort*   og     = (ushort*)  (ws + 12800000);   // og f16 [N,128]   12.8 MB
  ushort*   BfA    = (ushort*)  (ws + 25600000);   // 128 KB
  ushort*   BfB    = (ushort*)  (ws + 25800000);   // 32 KB
  ushort*   BfC    = (ushort*)  (ws + 25900000);   // 32 KB
  int*      cpart  = (int*)     (ws + 26000000);   // [NPB][256] counts, 128 KB
  int*      pairs  = (int*)     (ws + 26300000);   // bucket-major packed edges, 2.4 MB
  int*      es     = (int*)     (ws + 28700000);   // CSR src fallback, 2.4 MB
  float*    a_src  = (float*)   (ws + 31100000);   // 200 KB
  float*    a_dst  = (float*)   (ws + 31300000);   // 200 KB
  int*      gmS    = (int*)     (ws + 31500000);   // bucket bases S[256], 1 KB
  float*    bmaxS  = (float*)   (ws + 31600000);   // per-tile maxes, 12.5 KB
  float*    bmaxD  = (float*)   (ws + 31616000);   // 12.5 KB

  // 1: coarse histogram (block-major counts) || weight transposes
  pre_k<<<NPB + 256, 256, 0, stream>>>(W_in, W_gat, W_h, BfA, BfB, BfC, ei, cpart);
  // 2: fused gemmA+gemmB || bucket partition w/ LOCAL scan (blocks 0..NPB-1)
  gemmAB_k<<<NPB + NBG, 256, 0, stream>>>(x, BfA, BfB, b_in, gf,
      att_src, att_dst, a_src, a_dst, bmaxS, bmaxD, ei, cpart, pairs, gmS);
  // 3: fused fine-CSR + softmax-gather, 2 blocks/bucket (512 blocks -> all CUs)
  fineagg_k<<<2*NBUCK, 1024, 0, stream>>>(pairs, gmS, es, gf, a_src, a_dst,
      bmaxS, bmaxD, b_gat, og);
  // 4: gemmC
  gemmC_k<<<NBG, 256, 0, stream>>>(og, BfC, b_h, (float*)d_out, W_out, b_out);
}